// Round 11
// baseline (97.322 us; speedup 1.0000x reference)
//
#include <hip/hip_runtime.h>

// out: 4 tensors (32, 20, 14, 14, 14, 14) fp32 concatenated.
// Block = (n, q, d2); each block writes 4 contiguous chunks of 14*196 floats.
// R10 = R6 + NON-TEMPORAL stores (bypass L2 dirty-line lifecycle; stream to MC
// in wave-issue order, which the XCD remap already makes tight & ascending).
//   out_p[d3][ps] = F_i[d3][ps] * G_j[d3][ps]
//   F_i[d3][ps]   = A_i[d3,d4] * B_i[d3,d5]          (corner side)
//   A_i[d3][d4]   = 0.5*cor_i[0,pc]*cor_i[1+q,pc]*cor_i[23+d4,pc],  pc=d2*14+d3
//   B_i[d3][d5]   = cor_i[37+d5,pc]
//   G_j[d3][ps]   = T_j[ps] * cen_j[37+d3,ps]        (center side)
//   T_j[ps]       = cen_j[0,ps]*cen_j[1+q,ps]*cen_j[23+d2,ps]
// p1=F1*G1  p2=F2*G1  p3=F1*G2  p4=F2*G2

#define S_PER 24586240u            // 32*20*14^4 elements per tensor
#define TSTRIDE (51 * 196)
#define N_STRIDE (204 * 196)
#define NBLK 8960u                 // 32*20*14
#define NXCD 8u
#define BLK_PER_XCD (NBLK / NXCD)  // 1120

typedef float f32x4 __attribute__((ext_vector_type(4)));

__global__ __launch_bounds__(256) void plnet_kernel(const float* __restrict__ in,
                                                    float* __restrict__ out) {
    __shared__ __align__(16) float sT1[196];
    __shared__ __align__(16) float sT2[196];
    __shared__ float sA1[196], sA2[196];   // [d3*14 + d4]
    __shared__ float sB1[196], sB2[196];   // [d3*14 + d5]

    const unsigned raw = blockIdx.x;
    const unsigned b   = (raw % NXCD) * BLK_PER_XCD + raw / NXCD;

    const unsigned d2 = b % 14u;
    const unsigned nq = b / 14u;
    const unsigned q  = nq % 20u;
    const unsigned n  = nq / 20u;

    const float* g    = in + (size_t)n * N_STRIDE;
    const float* cor1 = g;
    const float* cor2 = g + TSTRIDE;
    const float* cen1 = g + 2 * TSTRIDE;
    const float* cen2 = g + 3 * TSTRIDE;

    const unsigned tid = threadIdx.x;

    // ---- Prologue: 6 small LDS tables, one barrier ----
    if (tid < 196u) {
        const unsigned ps = tid;
        sT1[ps] = cen1[ps] * cen1[(1u + q) * 196u + ps] * cen1[(23u + d2) * 196u + ps];
        sT2[ps] = cen2[ps] * cen2[(1u + q) * 196u + ps] * cen2[(23u + d2) * 196u + ps];
        const unsigned d3 = ps / 14u;
        const unsigned k  = ps - d3 * 14u;
        const unsigned pc = d2 * 14u + d3;
        const float k1 = 0.5f * cor1[pc] * cor1[(1u + q) * 196u + pc];
        const float k2 = 0.5f * cor2[pc] * cor2[(1u + q) * 196u + pc];
        sA1[ps] = k1 * cor1[(23u + k) * 196u + pc];
        sA2[ps] = k2 * cor2[(23u + k) * 196u + pc];
        sB1[ps] = cor1[(37u + k) * 196u + pc];
        sB2[ps] = cor2[(37u + k) * 196u + pc];
    }
    __syncthreads();

    // ---- Main: 686 float4-items over (d3, ps/4); contiguous NT stores ----
    const size_t chunk = ((size_t)(n * 20u + q) * 196u + d2 * 14u) * 196u;
    f32x4* o1 = (f32x4*)(out + chunk);
    f32x4* o2 = (f32x4*)(out + (size_t)S_PER + chunk);
    f32x4* o3 = (f32x4*)(out + 2u * (size_t)S_PER + chunk);
    f32x4* o4 = (f32x4*)(out + 3u * (size_t)S_PER + chunk);

    for (unsigned c = tid; c < 686u; c += 256u) {
        const unsigned d3 = c / 49u;
        const unsigned f  = c - d3 * 49u;
        const unsigned e  = 4u * f;          // ps of first element

        const float4 t1 = *(const float4*)&sT1[e];
        const float4 t2 = *(const float4*)&sT2[e];
        const float4 v1 = *(const float4*)&cen1[(37u + d3) * 196u + e];
        const float4 v2 = *(const float4*)&cen2[(37u + d3) * 196u + e];

        const float4 G1 = make_float4(t1.x * v1.x, t1.y * v1.y, t1.z * v1.z, t1.w * v1.w);
        const float4 G2 = make_float4(t2.x * v2.x, t2.y * v2.y, t2.z * v2.z, t2.w * v2.w);

        // per-element corner factors
        unsigned d4 = e / 14u;
        unsigned d5 = e - d4 * 14u;
        float F1[4], F2[4];
#pragma unroll
        for (int l = 0; l < 4; ++l) {
            F1[l] = sA1[d3 * 14u + d4] * sB1[d3 * 14u + d5];
            F2[l] = sA2[d3 * 14u + d4] * sB2[d3 * 14u + d5];
            ++d5;
            const unsigned carry = (d5 == 14u);
            d4 += carry;
            d5 = carry ? 0u : d5;
        }

        const f32x4 r1 = {F1[0] * G1.x, F1[1] * G1.y, F1[2] * G1.z, F1[3] * G1.w};
        const f32x4 r2 = {F2[0] * G1.x, F2[1] * G1.y, F2[2] * G1.z, F2[3] * G1.w};
        const f32x4 r3 = {F1[0] * G2.x, F1[1] * G2.y, F1[2] * G2.z, F1[3] * G2.w};
        const f32x4 r4 = {F2[0] * G2.x, F2[1] * G2.y, F2[2] * G2.z, F2[3] * G2.w};

        __builtin_nontemporal_store(r1, &o1[c]);
        __builtin_nontemporal_store(r2, &o2[c]);
        __builtin_nontemporal_store(r3, &o3[c]);
        __builtin_nontemporal_store(r4, &o4[c]);
    }
}

extern "C" void kernel_launch(void* const* d_in, const int* in_sizes, int n_in,
                              void* d_out, int out_size, void* d_ws, size_t ws_size,
                              hipStream_t stream) {
    const float* in = (const float*)d_in[0];
    float* out = (float*)d_out;
    dim3 grid(NBLK);               // one block per (n, q, d2), XCD-remapped inside
    dim3 block(256);
    plnet_kernel<<<grid, block, 0, stream>>>(in, out);
}

// Round 12
// 87.981 us; speedup vs baseline: 1.1062x; 1.1062x over previous
//
#include <hip/hip_runtime.h>

// out: 4 tensors (32, 20, 14, 14, 14, 14) fp32 concatenated (p = 0..3).
// R11: block = (p, n, q, half); handles d2 = half*7 + 0..6 of ONE tensor ->
// writes a single contiguous 7*2744-float (76.8 KB) region as 7-store bursts.
// XCD remap: each XCD sweeps one contiguous ~197 MB output range (1 window/XCD).
//   out_p[d2][d3][ps] = sA[d2][d3*14+d4] * sB[d2][d3*14+d5] * sT[d2][ps] * v[d3][ps]
//   sA = 0.5*cor_i[0,pc]*cor_i[1+q,pc]*cor_i[23+d4,pc]   pc = d2*14+d3
//   sB = cor_i[37+d5,pc]
//   sT = cen_j[0,ps]*cen_j[1+q,ps]*cen_j[23+d2,ps]
//   v  = cen_j[37+d3,ps]                                  (d2-independent!)
// p0=(cor1,cen1) p1=(cor2,cen1) p2=(cor1,cen2) p3=(cor2,cen2)

#define S_PER 24586240u            // 32*20*14^4 elements per tensor
#define TSTRIDE (51 * 196)
#define N_STRIDE (204 * 196)
#define NBLK 5120u                 // 4 * 32 * 20 * 2
#define NXCD 8u
#define BLK_PER_XCD (NBLK / NXCD)  // 640

__global__ __launch_bounds__(256) void plnet_kernel(const float* __restrict__ in,
                                                    float* __restrict__ out) {
    __shared__ __align__(16) float sT[7 * 196];
    __shared__ float sA[7 * 196];  // [d2k][d3*14 + d4]
    __shared__ float sB[7 * 196];  // [d2k][d3*14 + d5]

    // XCD-contiguous remap over flat chunk-group index.
    const unsigned raw = blockIdx.x;
    const unsigned cid = (raw & 7u) * BLK_PER_XCD + (raw >> 3);

    const unsigned p    = cid / 1280u;          // tensor 0..3
    const unsigned r    = cid - p * 1280u;
    const unsigned n    = r / 40u;
    const unsigned rr   = r - n * 40u;
    const unsigned q    = rr >> 1;
    const unsigned half = rr & 1u;
    const unsigned d2b  = half * 7u;

    const float* g   = in + (size_t)n * N_STRIDE;
    const float* cor = g + (size_t)(p & 1u) * TSTRIDE;
    const float* cen = g + (size_t)(2u + (p >> 1)) * TSTRIDE;

    const unsigned tid = threadIdx.x;

    // ---- Prologue: 21 small tables (7 d2 values), one barrier ----
    if (tid < 196u) {
        const unsigned ps = tid;
        const unsigned d3 = ps / 14u;
        const unsigned k  = ps - d3 * 14u;
        const float c0q = cen[ps] * cen[(1u + q) * 196u + ps];
#pragma unroll
        for (unsigned d2k = 0; d2k < 7u; ++d2k) {
            const unsigned d2 = d2b + d2k;
            sT[d2k * 196u + ps] = c0q * cen[(23u + d2) * 196u + ps];
            const unsigned pc = d2 * 14u + d3;
            sA[d2k * 196u + ps] = 0.5f * cor[pc] * cor[(1u + q) * 196u + pc]
                                       * cor[(23u + k) * 196u + pc];
            sB[d2k * 196u + ps] = cor[(37u + k) * 196u + pc];
        }
    }
    __syncthreads();

    // ---- Main: per item c, ONE v-load then 7-store burst into one region ----
    float4* o = (float4*)(out + (size_t)p * S_PER
                              + ((size_t)(n * 20u + q) * 196u + (size_t)d2b * 14u) * 196u);

    for (unsigned c = tid; c < 686u; c += 256u) {
        const unsigned d3 = c / 49u;
        const unsigned f  = c - d3 * 49u;
        const unsigned e  = 4u * f;          // ps of first element

        const float4 v = *(const float4*)&cen[(37u + d3) * 196u + e];

        // four (iA, iB) LDS index pairs, shared across all 7 d2
        unsigned d4 = e / 14u;
        unsigned d5 = e - d4 * 14u;
        unsigned iA[4], iB[4];
#pragma unroll
        for (int l = 0; l < 4; ++l) {
            iA[l] = d3 * 14u + d4;
            iB[l] = d3 * 14u + d5;
            ++d5;
            const unsigned carry = (d5 == 14u);
            d4 += carry;
            d5 = carry ? 0u : d5;
        }

#pragma unroll
        for (unsigned d2k = 0; d2k < 7u; ++d2k) {
            const unsigned base = d2k * 196u;
            const float4 t = *(const float4*)&sT[base + e];
            const float F0 = sA[base + iA[0]] * sB[base + iB[0]];
            const float F1 = sA[base + iA[1]] * sB[base + iB[1]];
            const float F2 = sA[base + iA[2]] * sB[base + iB[2]];
            const float F3 = sA[base + iA[3]] * sB[base + iB[3]];
            o[d2k * 686u + c] = make_float4(F0 * t.x * v.x, F1 * t.y * v.y,
                                            F2 * t.z * v.z, F3 * t.w * v.w);
        }
    }
}

extern "C" void kernel_launch(void* const* d_in, const int* in_sizes, int n_in,
                              void* d_out, int out_size, void* d_ws, size_t ws_size,
                              hipStream_t stream) {
    const float* in = (const float*)d_in[0];
    float* out = (float*)d_out;
    dim3 grid(NBLK);               // one block per (tensor, n, q, d2-half)
    dim3 block(256);
    plnet_kernel<<<grid, block, 0, stream>>>(in, out);
}